// Round 1
// baseline (856.826 us; speedup 1.0000x reference)
//
#include <hip/hip_runtime.h>
#include <math.h>

#define CH 96
#define DIN 192
#define NSTATE 16
#define DTRc 6
#define NPROJ 38
#define Bn 2
#define Ln 16384
#define NCc 256
#define CLc 64
#define LT 64

__device__ __forceinline__ float sigf(float x){ return 1.f/(1.f+__expf(-x)); }

// ---------------- LayerNorm: x (B,C,L) -> xn (B,L,C) ----------------
__global__ __launch_bounds__(256) void k_ln(const float* __restrict__ x,
    const float* __restrict__ g, const float* __restrict__ bb,
    float* __restrict__ xn){
  __shared__ float tile[CH*65];
  __shared__ float ps[4*64], ps2[4*64];
  __shared__ float mus[64], rss[64];
  int b = blockIdx.x / (Ln/LT);
  int l0 = (blockIdx.x % (Ln/LT)) * LT;
  int t = threadIdx.x;
  for(int i=t;i<CH*LT;i+=256){ int c=i/LT, j=i%LT; tile[c*65+j] = x[(b*CH+c)*Ln + l0 + j]; }
  __syncthreads();
  { int j = t & 63, part = t >> 6;
    float s=0.f, s2=0.f;
    #pragma unroll
    for(int c=part*24; c<part*24+24; ++c){ float v=tile[c*65+j]; s+=v; s2+=v*v; }
    ps[part*64+j]=s; ps2[part*64+j]=s2; }
  __syncthreads();
  if(t<64){
    float s=0.f,s2=0.f;
    #pragma unroll
    for(int p=0;p<4;p++){ s+=ps[p*64+t]; s2+=ps2[p*64+t]; }
    float mu = s*(1.f/CH);
    float var = s2*(1.f/CH) - mu*mu;
    mus[t]=mu; rss[t]=rsqrtf(var+1e-5f);
  }
  __syncthreads();
  for(int i=t;i<CH*LT;i+=256){ int j=i/CH, c=i%CH;
    float v=(tile[c*65+j]-mus[j])*rss[j]*g[c]+bb[c];
    xn[(b*Ln+l0+j)*CH + c]=v; }
}

// ---------------- In-proj GEMM: xn @ in_w.T -> xi (cols 0..191), silu(z) (cols 192..383) ----------------
__global__ __launch_bounds__(256) void k_inproj(const float* __restrict__ xn,
    const float* __restrict__ in_w, float* __restrict__ xi, float* __restrict__ zs, int dir){
  __shared__ float s_lds[LT*100];
  __shared__ float w_lds[96*100];
  int b = blockIdx.x / (Ln/LT);
  int l0 = (blockIdx.x % (Ln/LT)) * LT;
  int t = threadIdx.x;
  for(int i=t;i<LT*CH;i+=256){ int j=i/CH,c=i%CH; int p=l0+j; int po=dir?(Ln-1-p):p;
    s_lds[j*100+c]=xn[(b*Ln+po)*CH+c]; }
  int tcol=t&15, trow=t>>4;
  for(int q=0;q<4;q++){
    __syncthreads();
    for(int i=t;i<96*CH;i+=256){ int o=i/CH,c=i%CH; w_lds[o*100+c]=in_w[(q*96+o)*CH+c]; }
    __syncthreads();
    float acc[4][6];
    #pragma unroll
    for(int j=0;j<4;j++)
      #pragma unroll
      for(int k=0;k<6;k++) acc[j][k]=0.f;
    #pragma unroll 4
    for(int c=0;c<CH;c+=4){
      float4 sv[4];
      #pragma unroll
      for(int j=0;j<4;j++) sv[j]=*(const float4*)&s_lds[(trow+16*j)*100+c];
      #pragma unroll
      for(int k=0;k<6;k++){
        float4 wv=*(const float4*)&w_lds[(tcol+16*k)*100+c];
        #pragma unroll
        for(int j=0;j<4;j++)
          acc[j][k] += sv[j].x*wv.x+sv[j].y*wv.y+sv[j].z*wv.z+sv[j].w*wv.w;
      }
    }
    #pragma unroll
    for(int j=0;j<4;j++){
      int p=l0+trow+16*j;
      #pragma unroll
      for(int k=0;k<6;k++){
        int gc=q*96+tcol+16*k;
        if(gc<DIN) xi[(b*Ln+p)*DIN+gc]=acc[j][k];
        else { float v=acc[j][k]; zs[(b*Ln+p)*DIN+(gc-DIN)] = v*sigf(v); }
      }
    }
  }
}

// ---------------- causal depthwise conv(4) + bias + silu ----------------
__global__ __launch_bounds__(256) void k_conv(const float* __restrict__ xi,
    const float* __restrict__ cw, const float* __restrict__ cb, float* __restrict__ xc){
  int i = blockIdx.x*256 + threadIdx.x;
  if(i >= Bn*Ln*DIN) return;
  int d = i % DIN; int p = (i/DIN) % Ln; int b = i/(DIN*Ln);
  float acc = cb[d];
  #pragma unroll
  for(int k=0;k<4;k++){ int q = p-3+k; if(q>=0) acc += xi[(b*Ln+q)*DIN+d]*cw[d*4+k]; }
  xc[i] = acc * sigf(acc);
}

// ---------------- x-proj (192->38) + delta (6->192, softplus) ----------------
__global__ __launch_bounds__(256) void k_xproj(const float* __restrict__ xc,
    const float* __restrict__ xpw, const float* __restrict__ dtw, const float* __restrict__ dtb,
    float* __restrict__ delta, float* __restrict__ Bm, float* __restrict__ Cm){
  __shared__ float xt[LT*196];
  __shared__ float dbl[LT*40];
  int b = blockIdx.x/(Ln/LT); int l0=(blockIdx.x%(Ln/LT))*LT; int t=threadIdx.x;
  for(int i=t;i<LT*DIN;i+=256){ int j=i/DIN,c=i%DIN; xt[j*196+c]=xc[(b*Ln+l0+j)*DIN+c]; }
  __syncthreads();
  { int j=t>>2, og=t&3;
    float acc[10];
    #pragma unroll
    for(int k=0;k<10;k++) acc[k]=0.f;
    for(int c=0;c<DIN;c+=4){
      float4 xv=*(const float4*)&xt[j*196+c];
      #pragma unroll
      for(int k=0;k<10;k++){
        int o=og+4*k;
        if(o<NPROJ){
          float4 wv=*(const float4*)&xpw[o*DIN+c];
          acc[k]+=xv.x*wv.x+xv.y*wv.y+xv.z*wv.z+xv.w*wv.w;
        }
      }
    }
    #pragma unroll
    for(int k=0;k<10;k++){ int o=og+4*k; if(o<NPROJ) dbl[j*40+o]=acc[k]; }
  }
  __syncthreads();
  for(int i=t;i<LT*DIN;i+=256){ int j=i/DIN, d=i%DIN;
    float a=dtb[d];
    #pragma unroll
    for(int r=0;r<DTRc;r++) a += dbl[j*40+r]*dtw[d*DTRc+r];
    float sp = (a>20.f)? a : log1pf(__expf(a));
    delta[(b*Ln+l0+j)*DIN+d]=sp;
  }
  for(int i=t;i<LT*32;i+=256){ int j=i/32,qq=i%32;
    float v=dbl[j*40+DTRc+qq];
    if(qq<NSTATE) Bm[(b*Ln+l0+j)*NSTATE+qq]=v;
    else Cm[(b*Ln+l0+j)*NSTATE+qq-NSTATE]=v;
  }
}

// ---------------- scan pass 1: per-chunk (A_seg, B_seg) ----------------
__global__ __launch_bounds__(192) void k_scan1(const float* __restrict__ delta,
    const float* __restrict__ xc, const float* __restrict__ Bm,
    const float* __restrict__ A_log, float* __restrict__ Aseg, float* __restrict__ Bseg){
  int b = blockIdx.x / NCc; int ci = blockIdx.x % NCc; int d = threadIdx.x;
  __shared__ float bm[CLc*NSTATE];
  for(int i=d;i<CLc*NSTATE;i+=192) bm[i]=Bm[(b*Ln+ci*CLc)*NSTATE+i];
  float kA[NSTATE];
  { const float4* al=(const float4*)&A_log[d*NSTATE];
    #pragma unroll
    for(int v4=0;v4<4;v4++){ float4 a=al[v4];
      kA[v4*4+0]=-__expf(a.x)*1.4426950408889634f;
      kA[v4*4+1]=-__expf(a.y)*1.4426950408889634f;
      kA[v4*4+2]=-__expf(a.z)*1.4426950408889634f;
      kA[v4*4+3]=-__expf(a.w)*1.4426950408889634f; } }
  float h[NSTATE];
  #pragma unroll
  for(int n=0;n<NSTATE;n++) h[n]=0.f;
  float S=0.f;
  __syncthreads();
  const float* dp = delta + (b*Ln+ci*CLc)*DIN + d;
  const float* xp = xc    + (b*Ln+ci*CLc)*DIN + d;
  for(int ll=0;ll<CLc;ll++){
    float dl=dp[ll*DIN];
    float xv=xp[ll*DIN];
    float bx=dl*xv;
    S+=dl;
    float bv[NSTATE];
    { const float4* q=(const float4*)&bm[ll*NSTATE];
      #pragma unroll
      for(int v4=0;v4<4;v4++){ float4 a=q[v4]; bv[v4*4]=a.x; bv[v4*4+1]=a.y; bv[v4*4+2]=a.z; bv[v4*4+3]=a.w; } }
    #pragma unroll
    for(int n=0;n<NSTATE;n++){
      float a=exp2f(kA[n]*dl);
      h[n]=fmaf(a,h[n],bx*bv[n]);
    }
  }
  int base=((b*DIN+d)*NSTATE)*NCc + ci;
  #pragma unroll
  for(int n=0;n<NSTATE;n++){ Aseg[base+n*NCc]=exp2f(kA[n]*S); Bseg[base+n*NCc]=h[n]; }
}

// ---------------- scan pass 2: sequential chunk combine (in-place h_in into Bseg) ----------------
__global__ __launch_bounds__(256) void k_scan2(const float* __restrict__ Aseg, float* __restrict__ Bseg){
  int idx = blockIdx.x*256 + threadIdx.x;
  if(idx>=Bn*DIN*NSTATE) return;
  float h=0.f; int base = idx*NCc;
  for(int ci=0; ci<NCc; ++ci){
    float a=Aseg[base+ci], bs=Bseg[base+ci];
    Bseg[base+ci]=h;
    h = fmaf(a,h,bs);
  }
}

// ---------------- scan pass 3: replay from h_in, emit y*silu(z) into yacc ----------------
__global__ __launch_bounds__(192) void k_scan3(const float* __restrict__ delta,
    const float* __restrict__ xc, const float* __restrict__ Bm, const float* __restrict__ Cm,
    const float* __restrict__ hin, const float* __restrict__ A_log, const float* __restrict__ Dp,
    const float* __restrict__ zs, float* __restrict__ yacc, int dir){
  int b=blockIdx.x/NCc; int ci=blockIdx.x%NCc; int d=threadIdx.x;
  __shared__ float bm[CLc*NSTATE], cm[CLc*NSTATE];
  for(int i=d;i<CLc*NSTATE;i+=192){
    bm[i]=Bm[(b*Ln+ci*CLc)*NSTATE+i];
    cm[i]=Cm[(b*Ln+ci*CLc)*NSTATE+i];
  }
  float kA[NSTATE];
  { const float4* al=(const float4*)&A_log[d*NSTATE];
    #pragma unroll
    for(int v4=0;v4<4;v4++){ float4 a=al[v4];
      kA[v4*4+0]=-__expf(a.x)*1.4426950408889634f;
      kA[v4*4+1]=-__expf(a.y)*1.4426950408889634f;
      kA[v4*4+2]=-__expf(a.z)*1.4426950408889634f;
      kA[v4*4+3]=-__expf(a.w)*1.4426950408889634f; } }
  float Dd=Dp[d];
  float h[NSTATE];
  int base=((b*DIN+d)*NSTATE)*NCc+ci;
  #pragma unroll
  for(int n=0;n<NSTATE;n++) h[n]=hin[base+n*NCc];
  __syncthreads();
  const float* dp = delta + (b*Ln+ci*CLc)*DIN + d;
  const float* xp = xc    + (b*Ln+ci*CLc)*DIN + d;
  const float* zp = zs    + (b*Ln+ci*CLc)*DIN + d;
  for(int ll=0;ll<CLc;ll++){
    float dl=dp[ll*DIN];
    float xv=xp[ll*DIN];
    float zv=zp[ll*DIN];
    float bx=dl*xv;
    float bv[NSTATE], cv[NSTATE];
    { const float4* q=(const float4*)&bm[ll*NSTATE];
      const float4* r=(const float4*)&cm[ll*NSTATE];
      #pragma unroll
      for(int v4=0;v4<4;v4++){ float4 a=q[v4]; bv[v4*4]=a.x; bv[v4*4+1]=a.y; bv[v4*4+2]=a.z; bv[v4*4+3]=a.w;
                               float4 c=r[v4]; cv[v4*4]=c.x; cv[v4*4+1]=c.y; cv[v4*4+2]=c.z; cv[v4*4+3]=c.w; } }
    float y=0.f;
    #pragma unroll
    for(int n=0;n<NSTATE;n++){
      float a=exp2f(kA[n]*dl);
      h[n]=fmaf(a,h[n],bx*bv[n]);
      y=fmaf(h[n],cv[n],y);
    }
    y=fmaf(xv,Dd,y);
    float o=y*zv;
    int l=ci*CLc+ll;
    int p = dir? (Ln-1-l) : l;
    float* yp=&yacc[(b*Ln+p)*DIN+d];
    if(dir==0) *yp=o; else *yp+=o;
  }
}

// ---------------- out-proj GEMM (192->96) + residual, write (B,C,L) ----------------
__global__ __launch_bounds__(256) void k_out(const float* __restrict__ x,
    const float* __restrict__ ya, const float* __restrict__ ow, float* __restrict__ out){
  __shared__ float yt[LT*196];
  int b=blockIdx.x/(Ln/LT); int l0=(blockIdx.x%(Ln/LT))*LT; int t=threadIdx.x;
  for(int i=t;i<LT*DIN;i+=256){ int j=i/DIN,c=i%DIN; yt[j*196+c]=ya[(b*Ln+l0+j)*DIN+c]; }
  __syncthreads();
  int tp=t&15, tc=t>>4;
  float acc[6][4];
  #pragma unroll
  for(int j=0;j<6;j++)
    #pragma unroll
    for(int k=0;k<4;k++) acc[j][k]=0.f;
  for(int dd=0; dd<DIN; dd+=4){
    float4 yv[4];
    #pragma unroll
    for(int k=0;k<4;k++) yv[k]=*(const float4*)&yt[(tp+16*k)*196+dd];
    #pragma unroll
    for(int j=0;j<6;j++){
      float4 wv=*(const float4*)&ow[(tc+16*j)*DIN+dd];
      #pragma unroll
      for(int k=0;k<4;k++)
        acc[j][k]+=yv[k].x*wv.x+yv[k].y*wv.y+yv[k].z*wv.z+yv[k].w*wv.w;
    }
  }
  #pragma unroll
  for(int j=0;j<6;j++){ int c=tc+16*j;
    #pragma unroll
    for(int k=0;k<4;k++){ int p=l0+tp+16*k;
      int o=(b*CH+c)*Ln+p;
      out[o]=x[o]+acc[j][k]; } }
}

extern "C" void kernel_launch(void* const* d_in, const int* in_sizes, int n_in,
                              void* d_out, int out_size, void* d_ws, size_t ws_size,
                              hipStream_t stream){
  const float* x =(const float*)d_in[0];
  const float* g =(const float*)d_in[1];
  const float* be=(const float*)d_in[2];
  const float* ow=(const float*)d_in[3];
  const float* P[2][8];
  for(int dir=0;dir<2;dir++) for(int k=0;k<8;k++) P[dir][k]=(const float*)d_in[4+dir*8+k];
  float* ws=(float*)d_ws;
  size_t o=0;
  float* xn  = ws+o; o+=(size_t)Bn*Ln*CH;        // 3,145,728
  float* xi  = ws+o; o+=(size_t)Bn*Ln*DIN;       // 6,291,456
  float* zsb = ws+o; o+=(size_t)Bn*Ln*DIN;
  float* xcb = ws+o; o+=(size_t)Bn*Ln*DIN;
  float* de  = ws+o; o+=(size_t)Bn*Ln*DIN;
  float* Bmb = ws+o; o+=(size_t)Bn*Ln*NSTATE;
  float* Cmb = ws+o; o+=(size_t)Bn*Ln*NSTATE;
  float* ya  = ws+o; o+=(size_t)Bn*Ln*DIN;
  float* Asg = ws+o; o+=(size_t)Bn*DIN*NSTATE*NCc;
  float* Bsg = ws+o; o+=(size_t)Bn*DIN*NSTATE*NCc;
  float* outp=(float*)d_out;

  k_ln<<<dim3(Bn*(Ln/LT)),dim3(256),0,stream>>>(x,g,be,xn);
  for(int dir=0;dir<2;dir++){
    const float* in_w=P[dir][0]; const float* cw=P[dir][1]; const float* cb=P[dir][2];
    const float* xpw =P[dir][3]; const float* dtw=P[dir][4]; const float* dtb=P[dir][5];
    const float* Al  =P[dir][6]; const float* Dp =P[dir][7];
    k_inproj<<<dim3(Bn*(Ln/LT)),dim3(256),0,stream>>>(xn,in_w,xi,zsb,dir);
    k_conv  <<<dim3((Bn*Ln*DIN+255)/256),dim3(256),0,stream>>>(xi,cw,cb,xcb);
    k_xproj <<<dim3(Bn*(Ln/LT)),dim3(256),0,stream>>>(xcb,xpw,dtw,dtb,de,Bmb,Cmb);
    k_scan1 <<<dim3(Bn*NCc),dim3(192),0,stream>>>(de,xcb,Bmb,Al,Asg,Bsg);
    k_scan2 <<<dim3((Bn*DIN*NSTATE+255)/256),dim3(256),0,stream>>>(Asg,Bsg);
    k_scan3 <<<dim3(Bn*NCc),dim3(192),0,stream>>>(de,xcb,Bmb,Cmb,Bsg,Al,Dp,zsb,ya,dir);
  }
  k_out<<<dim3(Bn*(Ln/LT)),dim3(256),0,stream>>>(x,ya,ow,outp);
}

// Round 2
// 702.929 us; speedup vs baseline: 1.2189x; 1.2189x over previous
//
#include <hip/hip_runtime.h>
#include <math.h>

#define CH 96
#define DIN 192
#define NSTATE 16
#define DTRc 6
#define NPROJ 38
#define Bn 2
#define Ln 16384
#define NCc 256
#define CLc 64
#define LT 64
#define LP 32

__device__ __forceinline__ float sigf(float x){ return 1.f/(1.f+__expf(-x)); }

// ---------------- LayerNorm: x (B,C,L) -> xn (B,L,C) ----------------
__global__ __launch_bounds__(256) void k_ln(const float* __restrict__ x,
    const float* __restrict__ g, const float* __restrict__ bb,
    float* __restrict__ xn){
  __shared__ float tile[CH*65];
  __shared__ float ps[4*64], ps2[4*64];
  __shared__ float mus[64], rss[64];
  int b = blockIdx.x / (Ln/LT);
  int l0 = (blockIdx.x % (Ln/LT)) * LT;
  int t = threadIdx.x;
  for(int i=t;i<CH*LT;i+=256){ int c=i/LT, j=i%LT; tile[c*65+j] = x[(b*CH+c)*Ln + l0 + j]; }
  __syncthreads();
  { int j = t & 63, part = t >> 6;
    float s=0.f, s2=0.f;
    #pragma unroll
    for(int c=part*24; c<part*24+24; ++c){ float v=tile[c*65+j]; s+=v; s2+=v*v; }
    ps[part*64+j]=s; ps2[part*64+j]=s2; }
  __syncthreads();
  if(t<64){
    float s=0.f,s2=0.f;
    #pragma unroll
    for(int p=0;p<4;p++){ s+=ps[p*64+t]; s2+=ps2[p*64+t]; }
    float mu = s*(1.f/CH);
    float var = s2*(1.f/CH) - mu*mu;
    mus[t]=mu; rss[t]=rsqrtf(var+1e-5f);
  }
  __syncthreads();
  for(int i=t;i<CH*LT;i+=256){ int j=i/CH, c=i%CH;
    float v=(tile[c*65+j]-mus[j])*rss[j]*g[c]+bb[c];
    xn[(b*Ln+l0+j)*CH + c]=v; }
}

// ---------------- In-proj GEMM: xn @ in_w.T ----------------
// grid = Bn*(Ln/LP)*4 ; each block: one 96-row weight chunk q, LP positions.
// Weights staged in LDS once (38.4KB -> 4 blocks/CU); x streamed from L2/L3.
__global__ __launch_bounds__(256) void k_inproj(const float* __restrict__ xn,
    const float* __restrict__ in_w, float* __restrict__ xi, float* __restrict__ zs, int dir){
  __shared__ float w_s[96*100];
  int q  = blockIdx.x & 3;
  int rb = blockIdx.x >> 2;
  int b  = rb / (Ln/LP);
  int l0 = (rb % (Ln/LP)) * LP;
  int t = threadIdx.x;
  for(int i=t;i<96*CH;i+=256){ int o=i/CH,c=i%CH; w_s[o*100+c]=in_w[(q*96+o)*CH+c]; }
  __syncthreads();
  int og = t & 7, j = t >> 3;           // 8-way output split, 32 positions
  int p = l0 + j;
  int po = dir ? (Ln-1-p) : p;
  const float* xr = xn + (size_t)(b*Ln+po)*CH;
  float acc[12];
  #pragma unroll
  for(int k=0;k<12;k++) acc[k]=0.f;
  for(int c=0;c<CH;c+=4){
    float4 xv = *(const float4*)&xr[c];
    #pragma unroll
    for(int k=0;k<12;k++){
      float4 wv = *(const float4*)&w_s[(og+8*k)*100+c];
      acc[k] += xv.x*wv.x + xv.y*wv.y + xv.z*wv.z + xv.w*wv.w;
    }
  }
  #pragma unroll
  for(int k=0;k<12;k++){
    int gc = q*96 + og + 8*k;
    if(gc < DIN) xi[(size_t)(b*Ln+p)*DIN+gc] = acc[k];
    else { float v=acc[k]; zs[(size_t)(b*Ln+p)*DIN+(gc-DIN)] = v*sigf(v); }
  }
}

// ---------------- causal depthwise conv(4) + bias + silu ----------------
__global__ __launch_bounds__(256) void k_conv(const float* __restrict__ xi,
    const float* __restrict__ cw, const float* __restrict__ cb, float* __restrict__ xc){
  int i = blockIdx.x*256 + threadIdx.x;
  if(i >= Bn*Ln*DIN) return;
  int d = i % DIN; int p = (i/DIN) % Ln; int b = i/(DIN*Ln);
  float acc = cb[d];
  #pragma unroll
  for(int k=0;k<4;k++){ int q = p-3+k; if(q>=0) acc += xi[(b*Ln+q)*DIN+d]*cw[d*4+k]; }
  xc[i] = acc * sigf(acc);
}

// ---------------- x-proj (192->38) + delta (6->192, softplus) ----------------
// Weights (38x192 + 192x6) staged in LDS once; x streamed; LP=32 positions/block.
__global__ __launch_bounds__(256) void k_xproj(const float* __restrict__ xc,
    const float* __restrict__ xpw, const float* __restrict__ dtw, const float* __restrict__ dtb,
    float* __restrict__ delta, float* __restrict__ Bm, float* __restrict__ Cm){
  __shared__ float w_s[40*196];
  __shared__ float dtw_s[DIN*DTRc];
  __shared__ float dbl[LP*40];
  int b  = blockIdx.x / (Ln/LP);
  int l0 = (blockIdx.x % (Ln/LP)) * LP;
  int t = threadIdx.x;
  for(int i=t;i<NPROJ*DIN;i+=256){ int o=i/DIN,c=i%DIN; w_s[o*196+c]=xpw[i]; }
  for(int i=t;i<DIN*DTRc;i+=256) dtw_s[i]=dtw[i];
  __syncthreads();
  { int og = t & 7, j = t >> 3;
    const float* xr = xc + (size_t)(b*Ln+l0+j)*DIN;
    float acc[5];
    #pragma unroll
    for(int k=0;k<5;k++) acc[k]=0.f;
    for(int c=0;c<DIN;c+=4){
      float4 xv = *(const float4*)&xr[c];
      #pragma unroll
      for(int k=0;k<5;k++){
        float4 wv = *(const float4*)&w_s[(og+8*k)*196+c];
        acc[k] += xv.x*wv.x + xv.y*wv.y + xv.z*wv.z + xv.w*wv.w;
      }
    }
    #pragma unroll
    for(int k=0;k<5;k++){ int o=og+8*k; if(o<NPROJ) dbl[j*40+o]=acc[k]; }
  }
  __syncthreads();
  for(int i=t;i<LP*DIN;i+=256){ int j=i/DIN, d=i%DIN;
    float a=dtb[d];
    #pragma unroll
    for(int r=0;r<DTRc;r++) a += dbl[j*40+r]*dtw_s[d*DTRc+r];
    float sp = (a>20.f)? a : log1pf(__expf(a));
    delta[(size_t)(b*Ln+l0+j)*DIN+d]=sp;
  }
  for(int i=t;i<LP*32;i+=256){ int j=i/32,qq=i%32;
    float v=dbl[j*40+DTRc+qq];
    if(qq<NSTATE) Bm[(size_t)(b*Ln+l0+j)*NSTATE+qq]=v;
    else Cm[(size_t)(b*Ln+l0+j)*NSTATE+qq-NSTATE]=v;
  }
}

// ---------------- scan pass 1: per-chunk (A_seg, B_seg) ----------------
__global__ __launch_bounds__(192) void k_scan1(const float* __restrict__ delta,
    const float* __restrict__ xc, const float* __restrict__ Bm,
    const float* __restrict__ A_log, float* __restrict__ Aseg, float* __restrict__ Bseg){
  int b = blockIdx.x / NCc; int ci = blockIdx.x % NCc; int d = threadIdx.x;
  __shared__ float bm[CLc*NSTATE];
  for(int i=d;i<CLc*NSTATE;i+=192) bm[i]=Bm[(b*Ln+ci*CLc)*NSTATE+i];
  float kA[NSTATE];
  { const float4* al=(const float4*)&A_log[d*NSTATE];
    #pragma unroll
    for(int v4=0;v4<4;v4++){ float4 a=al[v4];
      kA[v4*4+0]=-__expf(a.x)*1.4426950408889634f;
      kA[v4*4+1]=-__expf(a.y)*1.4426950408889634f;
      kA[v4*4+2]=-__expf(a.z)*1.4426950408889634f;
      kA[v4*4+3]=-__expf(a.w)*1.4426950408889634f; } }
  float h[NSTATE];
  #pragma unroll
  for(int n=0;n<NSTATE;n++) h[n]=0.f;
  float S=0.f;
  __syncthreads();
  const float* dp = delta + (b*Ln+ci*CLc)*DIN + d;
  const float* xp = xc    + (b*Ln+ci*CLc)*DIN + d;
  for(int ll=0;ll<CLc;ll++){
    float dl=dp[ll*DIN];
    float xv=xp[ll*DIN];
    float bx=dl*xv;
    S+=dl;
    float bv[NSTATE];
    { const float4* q=(const float4*)&bm[ll*NSTATE];
      #pragma unroll
      for(int v4=0;v4<4;v4++){ float4 a=q[v4]; bv[v4*4]=a.x; bv[v4*4+1]=a.y; bv[v4*4+2]=a.z; bv[v4*4+3]=a.w; } }
    #pragma unroll
    for(int n=0;n<NSTATE;n++){
      float a=exp2f(kA[n]*dl);
      h[n]=fmaf(a,h[n],bx*bv[n]);
    }
  }
  int base=((b*DIN+d)*NSTATE)*NCc + ci;
  #pragma unroll
  for(int n=0;n<NSTATE;n++){ Aseg[base+n*NCc]=exp2f(kA[n]*S); Bseg[base+n*NCc]=h[n]; }
}

// ---------------- scan pass 2: sequential chunk combine ----------------
__global__ __launch_bounds__(256) void k_scan2(const float* __restrict__ Aseg, float* __restrict__ Bseg){
  int idx = blockIdx.x*256 + threadIdx.x;
  if(idx>=Bn*DIN*NSTATE) return;
  float h=0.f; int base = idx*NCc;
  for(int ci=0; ci<NCc; ++ci){
    float a=Aseg[base+ci], bs=Bseg[base+ci];
    Bseg[base+ci]=h;
    h = fmaf(a,h,bs);
  }
}

// ---------------- scan pass 3: replay from h_in, emit y*silu(z) ----------------
__global__ __launch_bounds__(192) void k_scan3(const float* __restrict__ delta,
    const float* __restrict__ xc, const float* __restrict__ Bm, const float* __restrict__ Cm,
    const float* __restrict__ hin, const float* __restrict__ A_log, const float* __restrict__ Dp,
    const float* __restrict__ zs, float* __restrict__ yacc, int dir){
  int b=blockIdx.x/NCc; int ci=blockIdx.x%NCc; int d=threadIdx.x;
  __shared__ float bm[CLc*NSTATE], cm[CLc*NSTATE];
  for(int i=d;i<CLc*NSTATE;i+=192){
    bm[i]=Bm[(b*Ln+ci*CLc)*NSTATE+i];
    cm[i]=Cm[(b*Ln+ci*CLc)*NSTATE+i];
  }
  float kA[NSTATE];
  { const float4* al=(const float4*)&A_log[d*NSTATE];
    #pragma unroll
    for(int v4=0;v4<4;v4++){ float4 a=al[v4];
      kA[v4*4+0]=-__expf(a.x)*1.4426950408889634f;
      kA[v4*4+1]=-__expf(a.y)*1.4426950408889634f;
      kA[v4*4+2]=-__expf(a.z)*1.4426950408889634f;
      kA[v4*4+3]=-__expf(a.w)*1.4426950408889634f; } }
  float Dd=Dp[d];
  float h[NSTATE];
  int base=((b*DIN+d)*NSTATE)*NCc+ci;
  #pragma unroll
  for(int n=0;n<NSTATE;n++) h[n]=hin[base+n*NCc];
  __syncthreads();
  const float* dp = delta + (b*Ln+ci*CLc)*DIN + d;
  const float* xp = xc    + (b*Ln+ci*CLc)*DIN + d;
  const float* zp = zs    + (b*Ln+ci*CLc)*DIN + d;
  for(int ll=0;ll<CLc;ll++){
    float dl=dp[ll*DIN];
    float xv=xp[ll*DIN];
    float zv=zp[ll*DIN];
    float bx=dl*xv;
    float bv[NSTATE], cv[NSTATE];
    { const float4* q=(const float4*)&bm[ll*NSTATE];
      const float4* r=(const float4*)&cm[ll*NSTATE];
      #pragma unroll
      for(int v4=0;v4<4;v4++){ float4 a=q[v4]; bv[v4*4]=a.x; bv[v4*4+1]=a.y; bv[v4*4+2]=a.z; bv[v4*4+3]=a.w;
                               float4 c=r[v4]; cv[v4*4]=c.x; cv[v4*4+1]=c.y; cv[v4*4+2]=c.z; cv[v4*4+3]=c.w; } }
    float y=0.f;
    #pragma unroll
    for(int n=0;n<NSTATE;n++){
      float a=exp2f(kA[n]*dl);
      h[n]=fmaf(a,h[n],bx*bv[n]);
      y=fmaf(h[n],cv[n],y);
    }
    y=fmaf(xv,Dd,y);
    float o=y*zv;
    int l=ci*CLc+ll;
    int p = dir? (Ln-1-l) : l;
    float* yp=&yacc[(size_t)(b*Ln+p)*DIN+d];
    if(dir==0) *yp=o; else *yp+=o;
  }
}

// ---------------- out-proj GEMM (192->96) + residual, write (B,C,L) ----------------
__global__ __launch_bounds__(256) void k_out(const float* __restrict__ x,
    const float* __restrict__ ya, const float* __restrict__ ow, float* __restrict__ out){
  __shared__ float yt[LT*196];
  int b=blockIdx.x/(Ln/LT); int l0=(blockIdx.x%(Ln/LT))*LT; int t=threadIdx.x;
  for(int i=t;i<LT*DIN;i+=256){ int j=i/DIN,c=i%DIN; yt[j*196+c]=ya[(size_t)(b*Ln+l0+j)*DIN+c]; }
  __syncthreads();
  int tp=t&15, tc=t>>4;
  float acc[6][4];
  #pragma unroll
  for(int j=0;j<6;j++)
    #pragma unroll
    for(int k=0;k<4;k++) acc[j][k]=0.f;
  for(int dd=0; dd<DIN; dd+=4){
    float4 yv[4];
    #pragma unroll
    for(int k=0;k<4;k++) yv[k]=*(const float4*)&yt[(tp+16*k)*196+dd];
    #pragma unroll
    for(int j=0;j<6;j++){
      float4 wv=*(const float4*)&ow[(tc+16*j)*DIN+dd];
      #pragma unroll
      for(int k=0;k<4;k++)
        acc[j][k]+=yv[k].x*wv.x+yv[k].y*wv.y+yv[k].z*wv.z+yv[k].w*wv.w;
    }
  }
  #pragma unroll
  for(int j=0;j<6;j++){ int c=tc+16*j;
    #pragma unroll
    for(int k=0;k<4;k++){ int p=l0+tp+16*k;
      int o=(b*CH+c)*Ln+p;
      out[o]=x[o]+acc[j][k]; } }
}

extern "C" void kernel_launch(void* const* d_in, const int* in_sizes, int n_in,
                              void* d_out, int out_size, void* d_ws, size_t ws_size,
                              hipStream_t stream){
  const float* x =(const float*)d_in[0];
  const float* g =(const float*)d_in[1];
  const float* be=(const float*)d_in[2];
  const float* ow=(const float*)d_in[3];
  const float* P[2][8];
  for(int dir=0;dir<2;dir++) for(int k=0;k<8;k++) P[dir][k]=(const float*)d_in[4+dir*8+k];
  float* ws=(float*)d_ws;
  size_t o=0;
  float* xn  = ws+o; o+=(size_t)Bn*Ln*CH;
  float* xi  = ws+o; o+=(size_t)Bn*Ln*DIN;
  float* zsb = ws+o; o+=(size_t)Bn*Ln*DIN;
  float* xcb = ws+o; o+=(size_t)Bn*Ln*DIN;
  float* de  = ws+o; o+=(size_t)Bn*Ln*DIN;
  float* Bmb = ws+o; o+=(size_t)Bn*Ln*NSTATE;
  float* Cmb = ws+o; o+=(size_t)Bn*Ln*NSTATE;
  float* ya  = ws+o; o+=(size_t)Bn*Ln*DIN;
  float* Asg = ws+o; o+=(size_t)Bn*DIN*NSTATE*NCc;
  float* Bsg = ws+o; o+=(size_t)Bn*DIN*NSTATE*NCc;
  float* outp=(float*)d_out;

  k_ln<<<dim3(Bn*(Ln/LT)),dim3(256),0,stream>>>(x,g,be,xn);
  for(int dir=0;dir<2;dir++){
    const float* in_w=P[dir][0]; const float* cw=P[dir][1]; const float* cb=P[dir][2];
    const float* xpw =P[dir][3]; const float* dtw=P[dir][4]; const float* dtb=P[dir][5];
    const float* Al  =P[dir][6]; const float* Dp =P[dir][7];
    k_inproj<<<dim3(Bn*(Ln/LP)*4),dim3(256),0,stream>>>(xn,in_w,xi,zsb,dir);
    k_conv  <<<dim3((Bn*Ln*DIN+255)/256),dim3(256),0,stream>>>(xi,cw,cb,xcb);
    k_xproj <<<dim3(Bn*(Ln/LP)),dim3(256),0,stream>>>(xcb,xpw,dtw,dtb,de,Bmb,Cmb);
    k_scan1 <<<dim3(Bn*NCc),dim3(192),0,stream>>>(de,xcb,Bmb,Al,Asg,Bsg);
    k_scan2 <<<dim3((Bn*DIN*NSTATE+255)/256),dim3(256),0,stream>>>(Asg,Bsg);
    k_scan3 <<<dim3(Bn*NCc),dim3(192),0,stream>>>(de,xcb,Bmb,Cmb,Bsg,Al,Dp,zsb,ya,dir);
  }
  k_out<<<dim3(Bn*(Ln/LT)),dim3(256),0,stream>>>(x,ya,ow,outp);
}

// Round 3
// 562.141 us; speedup vs baseline: 1.5242x; 1.2504x over previous
//
#include <hip/hip_runtime.h>
#include <math.h>

#define CH 96
#define DIN 192
#define NSTATE 16
#define DTRc 6
#define NPROJ 38
#define Bn 2
#define Ln 16384
#define NCc 512
#define CLc 32
#define SLAB (Bn*DIN*NSTATE)   /* 6144 floats per ci-slab */
#define LT 64
#define LP 32
#define LPI 128

__device__ __forceinline__ float sigf(float x){ return 1.f/(1.f+__expf(-x)); }

// ---------------- LayerNorm: x (B,C,L) -> xn (B,L,C) ----------------
__global__ __launch_bounds__(256) void k_ln(const float* __restrict__ x,
    const float* __restrict__ g, const float* __restrict__ bb,
    float* __restrict__ xn){
  __shared__ float tile[CH*65];
  __shared__ float ps[4*64], ps2[4*64];
  __shared__ float mus[64], rss[64];
  int b = blockIdx.x / (Ln/LT);
  int l0 = (blockIdx.x % (Ln/LT)) * LT;
  int t = threadIdx.x;
  for(int i=t;i<CH*LT;i+=256){ int c=i/LT, j=i%LT; tile[c*65+j] = x[(b*CH+c)*Ln + l0 + j]; }
  __syncthreads();
  { int j = t & 63, part = t >> 6;
    float s=0.f, s2=0.f;
    #pragma unroll
    for(int c=part*24; c<part*24+24; ++c){ float v=tile[c*65+j]; s+=v; s2+=v*v; }
    ps[part*64+j]=s; ps2[part*64+j]=s2; }
  __syncthreads();
  if(t<64){
    float s=0.f,s2=0.f;
    #pragma unroll
    for(int p=0;p<4;p++){ s+=ps[p*64+t]; s2+=ps2[p*64+t]; }
    float mu = s*(1.f/CH);
    float var = s2*(1.f/CH) - mu*mu;
    mus[t]=mu; rss[t]=rsqrtf(var+1e-5f);
  }
  __syncthreads();
  for(int i=t;i<CH*LT;i+=256){ int j=i/CH, c=i%CH;
    float v=(tile[c*65+j]-mus[j])*rss[j]*g[c]+bb[c];
    xn[(b*Ln+l0+j)*CH + c]=v; }
}

// ---------------- In-proj GEMM: xn @ in_w.T (4 positions/thread) ----------------
// grid = Bn*(Ln/LPI)*4 ; q selects 96-row weight chunk; weights in LDS, x streamed.
__global__ __launch_bounds__(256) void k_inproj(const float* __restrict__ xn,
    const float* __restrict__ in_w, float* __restrict__ xi, float* __restrict__ zs, int dir){
  __shared__ float w_s[96*100];
  int q  = blockIdx.x & 3;
  int rb = blockIdx.x >> 2;
  int b  = rb / (Ln/LPI);
  int l0 = (rb % (Ln/LPI)) * LPI;
  int t = threadIdx.x;
  for(int i=t;i<96*CH;i+=256){ int o=i/CH,c=i%CH; w_s[o*100+c]=in_w[(q*96+o)*CH+c]; }
  __syncthreads();
  int og = t & 7, jg = t >> 3;
  const float* xr[4];
  #pragma unroll
  for(int m=0;m<4;m++){
    int p = l0 + jg + 32*m;
    int po = dir ? (Ln-1-p) : p;
    xr[m] = xn + (size_t)(b*Ln+po)*CH;
  }
  float acc[4][12];
  #pragma unroll
  for(int m=0;m<4;m++)
    #pragma unroll
    for(int k=0;k<12;k++) acc[m][k]=0.f;
  for(int c=0;c<CH;c+=4){
    float4 xv[4];
    #pragma unroll
    for(int m=0;m<4;m++) xv[m]=*(const float4*)&xr[m][c];
    #pragma unroll
    for(int k=0;k<12;k++){
      float4 wv = *(const float4*)&w_s[(og+8*k)*100+c];
      #pragma unroll
      for(int m=0;m<4;m++)
        acc[m][k] += xv[m].x*wv.x + xv[m].y*wv.y + xv[m].z*wv.z + xv[m].w*wv.w;
    }
  }
  #pragma unroll
  for(int m=0;m<4;m++){
    int p = l0 + jg + 32*m;
    size_t rowo = (size_t)(b*Ln+p)*DIN;
    #pragma unroll
    for(int k=0;k<12;k++){
      int gc = q*96 + og + 8*k;
      if(gc < DIN) xi[rowo+gc] = acc[m][k];
      else { float v=acc[m][k]; zs[rowo+gc-DIN] = v*sigf(v); }
    }
  }
}

// ---------------- causal depthwise conv(4) + bias + silu ----------------
__global__ __launch_bounds__(256) void k_conv(const float* __restrict__ xi,
    const float* __restrict__ cw, const float* __restrict__ cb, float* __restrict__ xc){
  int i = blockIdx.x*256 + threadIdx.x;
  if(i >= Bn*Ln*DIN) return;
  int d = i % DIN; int p = (i/DIN) % Ln; int b = i/(DIN*Ln);
  float acc = cb[d];
  #pragma unroll
  for(int k=0;k<4;k++){ int q = p-3+k; if(q>=0) acc += xi[(b*Ln+q)*DIN+d]*cw[d*4+k]; }
  xc[i] = acc * sigf(acc);
}

// ---------------- x-proj (192->38) + delta (6->192, softplus) ----------------
__global__ __launch_bounds__(256) void k_xproj(const float* __restrict__ xc,
    const float* __restrict__ xpw, const float* __restrict__ dtw, const float* __restrict__ dtb,
    float* __restrict__ delta, float* __restrict__ Bm, float* __restrict__ Cm){
  __shared__ float w_s[40*196];
  __shared__ float dtw_s[DIN*DTRc];
  __shared__ float dbl[LP*40];
  int b  = blockIdx.x / (Ln/LP);
  int l0 = (blockIdx.x % (Ln/LP)) * LP;
  int t = threadIdx.x;
  for(int i=t;i<NPROJ*DIN;i+=256){ int o=i/DIN,c=i%DIN; w_s[o*196+c]=xpw[i]; }
  for(int i=t;i<DIN*DTRc;i+=256) dtw_s[i]=dtw[i];
  __syncthreads();
  { int og = t & 7, j = t >> 3;
    const float* xr = xc + (size_t)(b*Ln+l0+j)*DIN;
    float acc[5];
    #pragma unroll
    for(int k=0;k<5;k++) acc[k]=0.f;
    for(int c=0;c<DIN;c+=4){
      float4 xv = *(const float4*)&xr[c];
      #pragma unroll
      for(int k=0;k<5;k++){
        float4 wv = *(const float4*)&w_s[(og+8*k)*196+c];
        acc[k] += xv.x*wv.x + xv.y*wv.y + xv.z*wv.z + xv.w*wv.w;
      }
    }
    #pragma unroll
    for(int k=0;k<5;k++){ int o=og+8*k; if(o<NPROJ) dbl[j*40+o]=acc[k]; }
  }
  __syncthreads();
  for(int i=t;i<LP*DIN;i+=256){ int j=i/DIN, d=i%DIN;
    float a=dtb[d];
    #pragma unroll
    for(int r=0;r<DTRc;r++) a += dbl[j*40+r]*dtw_s[d*DTRc+r];
    float sp = (a>20.f)? a : log1pf(__expf(a));
    delta[(size_t)(b*Ln+l0+j)*DIN+d]=sp;
  }
  for(int i=t;i<LP*32;i+=256){ int j=i/32,qq=i%32;
    float v=dbl[j*40+DTRc+qq];
    if(qq<NSTATE) Bm[(size_t)(b*Ln+l0+j)*NSTATE+qq]=v;
    else Cm[(size_t)(b*Ln+l0+j)*NSTATE+qq-NSTATE]=v;
  }
}

// ---------------- scan pass 1: per-chunk (A_seg, B_seg), layout [ci][b][d][n] ----------------
__global__ __launch_bounds__(192) void k_scan1(const float* __restrict__ delta,
    const float* __restrict__ xc, const float* __restrict__ Bm,
    const float* __restrict__ A_log, float* __restrict__ Aseg, float* __restrict__ Bseg){
  int b = blockIdx.x / NCc; int ci = blockIdx.x % NCc; int d = threadIdx.x;
  __shared__ float bm[CLc*NSTATE];
  for(int i=d;i<CLc*NSTATE;i+=192) bm[i]=Bm[(size_t)(b*Ln+ci*CLc)*NSTATE+i];
  float kA[NSTATE];
  { const float4* al=(const float4*)&A_log[d*NSTATE];
    #pragma unroll
    for(int v4=0;v4<4;v4++){ float4 a=al[v4];
      kA[v4*4+0]=-__expf(a.x)*1.4426950408889634f;
      kA[v4*4+1]=-__expf(a.y)*1.4426950408889634f;
      kA[v4*4+2]=-__expf(a.z)*1.4426950408889634f;
      kA[v4*4+3]=-__expf(a.w)*1.4426950408889634f; } }
  float h[NSTATE];
  #pragma unroll
  for(int n=0;n<NSTATE;n++) h[n]=0.f;
  float S=0.f;
  __syncthreads();
  const float* dp = delta + ((size_t)b*Ln+ci*CLc)*DIN + d;
  const float* xp = xc    + ((size_t)b*Ln+ci*CLc)*DIN + d;
  for(int ll=0;ll<CLc;ll++){
    float dl=dp[ll*DIN];
    float xv=xp[ll*DIN];
    float bx=dl*xv;
    S+=dl;
    float bv[NSTATE];
    { const float4* qq=(const float4*)&bm[ll*NSTATE];
      #pragma unroll
      for(int v4=0;v4<4;v4++){ float4 a=qq[v4]; bv[v4*4]=a.x; bv[v4*4+1]=a.y; bv[v4*4+2]=a.z; bv[v4*4+3]=a.w; } }
    #pragma unroll
    for(int n=0;n<NSTATE;n++){
      float a=exp2f(kA[n]*dl);
      h[n]=fmaf(a,h[n],bx*bv[n]);
    }
  }
  size_t wb = (((size_t)ci*Bn + b)*DIN + d)*NSTATE;
  #pragma unroll
  for(int v4=0;v4<4;v4++){
    float4 av, bv4;
    av.x=exp2f(kA[v4*4+0]*S); av.y=exp2f(kA[v4*4+1]*S);
    av.z=exp2f(kA[v4*4+2]*S); av.w=exp2f(kA[v4*4+3]*S);
    bv4.x=h[v4*4+0]; bv4.y=h[v4*4+1]; bv4.z=h[v4*4+2]; bv4.w=h[v4*4+3];
    *(float4*)&Aseg[wb+v4*4]=av;
    *(float4*)&Bseg[wb+v4*4]=bv4;
  }
}

// ---------------- scan pass 2: sequential chunk combine, coalesced ----------------
// grid = Bn*(DIN/16) = 24 blocks; 256 threads = 16 d x 16 n.
__global__ __launch_bounds__(256) void k_scan2(const float* __restrict__ Aseg,
    const float* __restrict__ Bseg, float* __restrict__ Hseg){
  int t = threadIdx.x;
  int dg = blockIdx.x % (DIN/16);
  int b  = blockIdx.x / (DIN/16);
  int d = dg*16 + (t>>4);
  int n = t & 15;
  size_t off = ((size_t)b*DIN + d)*NSTATE + n;
  float h=0.f;
  for(int ci=0; ci<NCc; ++ci){
    size_t idx = (size_t)ci*SLAB + off;
    float a=Aseg[idx], bb=Bseg[idx];
    Hseg[idx]=h;
    h = fmaf(a,h,bb);
  }
}

// ---------------- scan pass 3: replay from h_in, emit y*silu(z) ----------------
__global__ __launch_bounds__(192) void k_scan3(const float* __restrict__ delta,
    const float* __restrict__ xc, const float* __restrict__ Bm, const float* __restrict__ Cm,
    const float* __restrict__ Hseg, const float* __restrict__ A_log, const float* __restrict__ Dp,
    const float* __restrict__ zs, float* __restrict__ yacc, int dir){
  int b=blockIdx.x/NCc; int ci=blockIdx.x%NCc; int d=threadIdx.x;
  __shared__ float bm[CLc*NSTATE], cm[CLc*NSTATE];
  for(int i=d;i<CLc*NSTATE;i+=192){
    bm[i]=Bm[(size_t)(b*Ln+ci*CLc)*NSTATE+i];
    cm[i]=Cm[(size_t)(b*Ln+ci*CLc)*NSTATE+i];
  }
  float kA[NSTATE];
  { const float4* al=(const float4*)&A_log[d*NSTATE];
    #pragma unroll
    for(int v4=0;v4<4;v4++){ float4 a=al[v4];
      kA[v4*4+0]=-__expf(a.x)*1.4426950408889634f;
      kA[v4*4+1]=-__expf(a.y)*1.4426950408889634f;
      kA[v4*4+2]=-__expf(a.z)*1.4426950408889634f;
      kA[v4*4+3]=-__expf(a.w)*1.4426950408889634f; } }
  float Dd=Dp[d];
  float h[NSTATE];
  { size_t rb = (((size_t)ci*Bn + b)*DIN + d)*NSTATE;
    const float4* hp=(const float4*)&Hseg[rb];
    #pragma unroll
    for(int v4=0;v4<4;v4++){ float4 a=hp[v4]; h[v4*4]=a.x; h[v4*4+1]=a.y; h[v4*4+2]=a.z; h[v4*4+3]=a.w; } }
  __syncthreads();
  const float* dp = delta + ((size_t)b*Ln+ci*CLc)*DIN + d;
  const float* xp = xc    + ((size_t)b*Ln+ci*CLc)*DIN + d;
  const float* zp = zs    + ((size_t)b*Ln+ci*CLc)*DIN + d;
  for(int ll=0;ll<CLc;ll++){
    float dl=dp[ll*DIN];
    float xv=xp[ll*DIN];
    float zv=zp[ll*DIN];
    float bx=dl*xv;
    float bv[NSTATE], cv[NSTATE];
    { const float4* qq=(const float4*)&bm[ll*NSTATE];
      const float4* rr=(const float4*)&cm[ll*NSTATE];
      #pragma unroll
      for(int v4=0;v4<4;v4++){ float4 a=qq[v4]; bv[v4*4]=a.x; bv[v4*4+1]=a.y; bv[v4*4+2]=a.z; bv[v4*4+3]=a.w;
                               float4 c=rr[v4]; cv[v4*4]=c.x; cv[v4*4+1]=c.y; cv[v4*4+2]=c.z; cv[v4*4+3]=c.w; } }
    float y=0.f;
    #pragma unroll
    for(int n=0;n<NSTATE;n++){
      float a=exp2f(kA[n]*dl);
      h[n]=fmaf(a,h[n],bx*bv[n]);
      y=fmaf(h[n],cv[n],y);
    }
    y=fmaf(xv,Dd,y);
    float o=y*zv;
    int l=ci*CLc+ll;
    int p = dir? (Ln-1-l) : l;
    float* yp=&yacc[(size_t)(b*Ln+p)*DIN+d];
    if(dir==0) *yp=o; else *yp+=o;
  }
}

// ---------------- out-proj GEMM (192->96) + residual, write (B,C,L) ----------------
__global__ __launch_bounds__(256) void k_out(const float* __restrict__ x,
    const float* __restrict__ ya, const float* __restrict__ ow, float* __restrict__ out){
  __shared__ float yt[LT*196];
  int b=blockIdx.x/(Ln/LT); int l0=(blockIdx.x%(Ln/LT))*LT; int t=threadIdx.x;
  for(int i=t;i<LT*DIN;i+=256){ int j=i/DIN,c=i%DIN; yt[j*196+c]=ya[(size_t)(b*Ln+l0+j)*DIN+c]; }
  __syncthreads();
  int tp=t&15, tc=t>>4;
  float acc[6][4];
  #pragma unroll
  for(int j=0;j<6;j++)
    #pragma unroll
    for(int k=0;k<4;k++) acc[j][k]=0.f;
  for(int dd=0; dd<DIN; dd+=4){
    float4 yv[4];
    #pragma unroll
    for(int k=0;k<4;k++) yv[k]=*(const float4*)&yt[(tp+16*k)*196+dd];
    #pragma unroll
    for(int j=0;j<6;j++){
      float4 wv=*(const float4*)&ow[(tc+16*j)*DIN+dd];
      #pragma unroll
      for(int k=0;k<4;k++)
        acc[j][k]+=yv[k].x*wv.x+yv[k].y*wv.y+yv[k].z*wv.z+yv[k].w*wv.w;
    }
  }
  #pragma unroll
  for(int j=0;j<6;j++){ int c=tc+16*j;
    #pragma unroll
    for(int k=0;k<4;k++){ int p=l0+tp+16*k;
      int o=(b*CH+c)*Ln+p;
      out[o]=x[o]+acc[j][k]; } }
}

extern "C" void kernel_launch(void* const* d_in, const int* in_sizes, int n_in,
                              void* d_out, int out_size, void* d_ws, size_t ws_size,
                              hipStream_t stream){
  const float* x =(const float*)d_in[0];
  const float* g =(const float*)d_in[1];
  const float* be=(const float*)d_in[2];
  const float* ow=(const float*)d_in[3];
  const float* P[2][8];
  for(int dir=0;dir<2;dir++) for(int k=0;k<8;k++) P[dir][k]=(const float*)d_in[4+dir*8+k];
  float* ws=(float*)d_ws;
  size_t o=0;
  float* xn  = ws+o; o+=(size_t)Bn*Ln*CH;
  float* xi  = ws+o; o+=(size_t)Bn*Ln*DIN;   // also hosts Asg+Bsg during scans (xi dead then)
  float* zsb = ws+o; o+=(size_t)Bn*Ln*DIN;
  float* xcb = ws+o; o+=(size_t)Bn*Ln*DIN;
  float* de  = ws+o; o+=(size_t)Bn*Ln*DIN;
  float* Bmb = ws+o; o+=(size_t)Bn*Ln*NSTATE;
  float* Cmb = ws+o; o+=(size_t)Bn*Ln*NSTATE;
  float* ya  = ws+o; o+=(size_t)Bn*Ln*DIN;
  float* Hsg = ws+o; o+=(size_t)SLAB*NCc;    // 3,145,728 (total footprint == round-1's proven 155.2MB)
  float* Asg = xi;                            // 3,145,728 floats
  float* Bsg = xi + (size_t)SLAB*NCc/ (size_t)1; // offset by SLAB*NCc
  Bsg = xi + (size_t)Bn*DIN*NSTATE*NCc;       // = xi + 3,145,728
  float* outp=(float*)d_out;

  k_ln<<<dim3(Bn*(Ln/LT)),dim3(256),0,stream>>>(x,g,be,xn);
  for(int dir=0;dir<2;dir++){
    const float* in_w=P[dir][0]; const float* cw=P[dir][1]; const float* cb=P[dir][2];
    const float* xpw =P[dir][3]; const float* dtw=P[dir][4]; const float* dtb=P[dir][5];
    const float* Al  =P[dir][6]; const float* Dp =P[dir][7];
    k_inproj<<<dim3(Bn*(Ln/LPI)*4),dim3(256),0,stream>>>(xn,in_w,xi,zsb,dir);
    k_conv  <<<dim3((Bn*Ln*DIN+255)/256),dim3(256),0,stream>>>(xi,cw,cb,xcb);
    k_xproj <<<dim3(Bn*(Ln/LP)),dim3(256),0,stream>>>(xcb,xpw,dtw,dtb,de,Bmb,Cmb);
    k_scan1 <<<dim3(Bn*NCc),dim3(192),0,stream>>>(de,xcb,Bmb,Al,Asg,Bsg);
    k_scan2 <<<dim3(Bn*(DIN/16)),dim3(256),0,stream>>>(Asg,Bsg,Hsg);
    k_scan3 <<<dim3(Bn*NCc),dim3(192),0,stream>>>(de,xcb,Bmb,Cmb,Hsg,Al,Dp,zsb,ya,dir);
  }
  k_out<<<dim3(Bn*(Ln/LT)),dim3(256),0,stream>>>(x,ya,ow,outp);
}